// Round 1
// baseline (37825.107 us; speedup 1.0000x reference)
//
#include <hip/hip_runtime.h>
#include <cstdint>
#include <cstddef>

namespace {

constexpr int D   = 1024;
constexpr int NB  = 20;
constexpr int B   = 8;
constexpr int S   = 2048;
constexpr int NWG = 32;      // workgroups cooperating per batch
constexpr float EPS = 1e-8f;

typedef __attribute__((ext_vector_type(4))) float f4_t;
typedef __attribute__((ext_vector_type(8))) short s8_t;

__device__ __forceinline__ unsigned short f2bf(float f) {
  unsigned u = __float_as_uint(f);
  u += 0x7fffu + ((u >> 16) & 1u);     // RNE
  return (unsigned short)(u >> 16);
}
__device__ __forceinline__ float bf2f(unsigned short h) {
  return __uint_as_float(((unsigned)h) << 16);
}

#define MFMA(a, b, c) __builtin_amdgcn_mfma_f32_16x16x32_bf16((a), (b), (c), 0, 0, 0)

// ---- workspace layout (bytes) ----
constexpr size_t OFF_HBUF = 0;                                   // u32 [2][B][NB][512]  (bf16 pairs)
constexpr size_t OFF_NORM = OFF_HBUF + 2ull * B * NB * 512 * 4;  // f32 [2][B][NB][NWG]
constexpr size_t OFF_CTR  = OFF_NORM + 2ull * B * NB * NWG * 4;  // i32 [B][16]
constexpr size_t OFF_KV   = OFF_CTR + (size_t)B * 16 * 4;        // f32 [NB][D]
constexpr size_t OFF_KX   = OFF_KV + (size_t)NB * D * 4;         // f32 [B*S][NB]
constexpr size_t OFF_UHI  = OFF_KX + (size_t)B * S * NB * 4;     // u16 [D][D]
constexpr size_t OFF_ULO  = OFF_UHI + (size_t)D * D * 2;
constexpr size_t OFF_WHI  = OFF_ULO + (size_t)D * D * 2;
constexpr size_t OFF_WLO  = OFF_WHI + (size_t)D * D * 2;

// ---------------- init kernels ----------------

__global__ void k_convert(const float* __restrict__ U, const float* __restrict__ W,
                          unsigned short* __restrict__ Uhi, unsigned short* __restrict__ Ulo,
                          unsigned short* __restrict__ Whi, unsigned short* __restrict__ Wlo) {
  const int n = D * D;
  for (int i = blockIdx.x * blockDim.x + threadIdx.x; i < n; i += gridDim.x * blockDim.x) {
    float u = U[i];
    unsigned short h = f2bf(u);
    Uhi[i] = h;
    Ulo[i] = f2bf(u - bf2f(h));
    float w = W[i];
    h = f2bf(w);
    Whi[i] = h;
    Wlo[i] = f2bf(w - bf2f(h));
  }
}

// KV[i][j] = keys[i] . V[j]
__global__ void k_kv(const float* __restrict__ keys, const float* __restrict__ V,
                     float* __restrict__ KV) {
  const int tid = threadIdx.x;
  const int j = blockIdx.x * 64 + (tid >> 2);
  const int kq = tid & 3;
  const f4_t* v4 = (const f4_t*)(V + (size_t)j * D + kq * 256);
  const f4_t* k4base = (const f4_t*)keys;
  float acc[NB];
#pragma unroll
  for (int i = 0; i < NB; ++i) acc[i] = 0.f;
  for (int q = 0; q < 64; ++q) {
    const f4_t v = v4[q];
#pragma unroll
    for (int i = 0; i < NB; ++i) {
      const f4_t kk = k4base[i * 256 + kq * 64 + q];
      acc[i] += kk[0] * v[0] + kk[1] * v[1] + kk[2] * v[2] + kk[3] * v[3];
    }
  }
#pragma unroll
  for (int i = 0; i < NB; ++i) {
    float s = acc[i];
    s += __shfl_xor(s, 1);
    s += __shfl_xor(s, 2);
    if (kq == 0) KV[(size_t)i * D + j] = s;
  }
}

// KX[bt][i] = keys[i] . (e[bt]+m[bt])
__global__ void k_kx(const float* __restrict__ e, const float* __restrict__ m,
                     const float* __restrict__ keys, float* __restrict__ KX) {
  __shared__ f4_t xs[256];
  __shared__ float part[NB][8];
  const int bt = blockIdx.x, tid = threadIdx.x;
  xs[tid] = ((const f4_t*)e)[(size_t)bt * 256 + tid] + ((const f4_t*)m)[(size_t)bt * 256 + tid];
  __syncthreads();
  if (tid < 160) {
    const int i = tid >> 3, s8 = tid & 7;
    float acc = 0.f;
    const f4_t* k4 = (const f4_t*)keys + i * 256 + s8 * 32;
    for (int q = 0; q < 32; ++q) {
      const f4_t kk = k4[q];
      const f4_t xx = xs[s8 * 32 + q];
      acc += kk[0] * xx[0] + kk[1] * xx[1] + kk[2] * xx[2] + kk[3] * xx[3];
    }
    part[i][s8] = acc;
  }
  __syncthreads();
  if (tid < NB) {
    float s = 0.f;
#pragma unroll
    for (int q = 0; q < 8; ++q) s += part[tid][q];
    KX[(size_t)bt * NB + tid] = s;
  }
}

__global__ void k_state(const float* __restrict__ state, unsigned* __restrict__ Hbuf,
                        float* __restrict__ NormP, int* __restrict__ ctr) {
  const int idx = blockIdx.x * 256 + threadIdx.x;
  if (idx < B * NB * 512) {
    const int r = idx % (NB * 512);
    const int i = r >> 9, d2 = (r & 511) << 1;
    const unsigned short a = f2bf(state[i * D + d2]);
    const unsigned short c = f2bf(state[i * D + d2 + 1]);
    Hbuf[idx] = (unsigned)a | ((unsigned)c << 16);
  }
  const int j = idx - B * NB * 512;
  if (j >= 0 && j < B * NB * NWG) NormP[j] = 1.0f / 32.0f;  // sumsq=1 -> s=1 exactly
  const int q = idx - B * NB * 512 - B * NB * NWG;
  if (q >= 0 && q < B * 16) ctr[q] = 0;
}

// ---------------- persistent recurrence kernel ----------------

struct __align__(16) LdsT {
  unsigned short xtA[2][D];        // rows: 0=xt_hi, 1=xt_lo (bf16)
  float credU[2][2][2][16][20];    // [copy][mt][nt][row][col pad20]
  float wxAcc[2][2][16];           // [copy][nt][col]
  float gAcc[2][2][16];            // [copy][mt][col]
  float KVs[NB][32];
  float ownH[NB][32];              // fp32 unnormalized h slice (exact path)
  float sL[NB];
  float gL[NB];
  float wxS[32];
  float rowsq[NB][8];
  unsigned short hnA[NB * D];      // bf16 normalized h, k-block swizzled by (row&15)
};

__launch_bounds__(256, 1)
__global__ void k_rnn(const float* __restrict__ e, const float* __restrict__ m,
                      const float* __restrict__ state,
                      const float* __restrict__ KX, const float* __restrict__ KV,
                      const unsigned short* __restrict__ Uhi, const unsigned short* __restrict__ Ulo,
                      const unsigned short* __restrict__ Whi, const unsigned short* __restrict__ Wlo,
                      unsigned* __restrict__ Hbuf, float* __restrict__ NormP,
                      int* __restrict__ ctr, float* __restrict__ out) {
  __shared__ LdsT L;
  const int tid = threadIdx.x;
  const int b = blockIdx.x & 7;    // consecutive blocks -> different XCDs: batch stays XCD-local (perf heuristic only)
  const int wg = blockIdx.x >> 3;  // column-slice id, owns cols [wg*32, wg*32+32)
  const int wv = tid >> 6;
  const int ln = tid & 63;
  const int l15 = ln & 15;
  const int lo4 = ln >> 4;

  // resident B-fragments: U and W column slices, bf16 hi/lo, this wave's k-chunk [wv*256, wv*256+256)
  s8_t BUh[2][8], BUl[2][8], BWh[2][8], BWl[2][8];
  {
    const int rowb = (wg << 5) + l15;
#pragma unroll
    for (int nt = 0; nt < 2; ++nt)
#pragma unroll
      for (int kf = 0; kf < 8; ++kf) {
        const size_t off = (size_t)(rowb + nt * 16) * D + (wv << 8) + (kf << 5) + (lo4 << 3);
        BUh[nt][kf] = *(const s8_t*)(Uhi + off);
        BUl[nt][kf] = *(const s8_t*)(Ulo + off);
        BWh[nt][kf] = *(const s8_t*)(Whi + off);
        BWl[nt][kf] = *(const s8_t*)(Wlo + off);
      }
  }
  if (tid < 160) {
    const int i = tid >> 3, c4 = (tid & 7) << 2;
    *(f4_t*)&L.ownH[i][c4] = *(const f4_t*)(state + (size_t)i * D + (wg << 5) + c4);
    *(f4_t*)&L.KVs[i][c4] = *(const f4_t*)(KV + (size_t)i * D + (wg << 5) + c4);
  }
  __syncthreads();

  int* const myctr = ctr + b * 16;

  for (int t = 0; t < S; ++t) {
    const int cur = t & 1, nxt = cur ^ 1;

    // ---- phase A: build xt (hi/lo bf16) + norm sumsq partials ----
    {
      const f4_t ev = ((const f4_t*)e)[(size_t)(b * S + t) * 256 + tid];
      const f4_t mv = ((const f4_t*)m)[(size_t)(b * S + t) * 256 + tid];
      const f4_t x = ev + mv;
      const unsigned short h0 = f2bf(x[0]), h1 = f2bf(x[1]), h2 = f2bf(x[2]), h3 = f2bf(x[3]);
      const unsigned short u0 = f2bf(x[0] - bf2f(h0)), u1 = f2bf(x[1] - bf2f(h1));
      const unsigned short u2 = f2bf(x[2] - bf2f(h2)), u3 = f2bf(x[3] - bf2f(h3));
      const int kp = tid << 2;
      *(unsigned*)&L.xtA[0][kp] = (unsigned)h0 | ((unsigned)h1 << 16);
      *(unsigned*)&L.xtA[0][kp + 2] = (unsigned)h2 | ((unsigned)h3 << 16);
      *(unsigned*)&L.xtA[1][kp] = (unsigned)u0 | ((unsigned)u1 << 16);
      *(unsigned*)&L.xtA[1][kp + 2] = (unsigned)u2 | ((unsigned)u3 << 16);
    }
    if (tid < 160) {
      const int i = tid >> 3, w4 = (tid & 7) << 2;
      float* np = NormP + ((size_t)(cur * B + b) * NB + i) * NWG + w4;
      float sq = 0.f;
#pragma unroll
      for (int q = 0; q < 4; ++q)
        sq += __hip_atomic_load(np + q, __ATOMIC_RELAXED, __HIP_MEMORY_SCOPE_AGENT);
      L.rowsq[i][tid & 7] = sq;
    }
    __syncthreads();
    if (tid < NB) {
      float sq = 0.f;
#pragma unroll
      for (int q = 0; q < 8; ++q) sq += L.rowsq[tid][q];
      L.sL[tid] = 1.0f / (sqrtf(sq) + EPS);
    }
    __syncthreads();

    // ---- broadcast: raw bf16 h (device-coherent atomic loads) -> scaled -> LDS swizzled ----
    {
      unsigned* hb = Hbuf + (size_t)(cur * B + b) * (NB * 512);
#pragma unroll 4
      for (int j = 0; j < 40; ++j) {
        const int di = tid + (j << 8);
        const unsigned dw = __hip_atomic_load(hb + di, __ATOMIC_RELAXED, __HIP_MEMORY_SCOPE_AGENT);
        const int i = di >> 9;
        const float s = L.sL[i];
        const float v0 = bf2f((unsigned short)(dw & 0xffffu)) * s;
        const float v1 = bf2f((unsigned short)(dw >> 16)) * s;
        const int dpos = di & 511;
        const int blk = dpos >> 2;
        const int sub = (dpos & 3) << 1;
        const int eo = (i << 10) + ((blk ^ (i & 15)) << 3) + sub;
        *(unsigned*)&L.hnA[eo] = (unsigned)f2bf(v0) | ((unsigned)f2bf(v1) << 16);
      }
    }
    __syncthreads();

    // ---- MFMA: h@U^T (split U), Wx (packed xt hi/lo rows, split W), gate h.xt ----
    f4_t cU00 = {0, 0, 0, 0}, cU01 = {0, 0, 0, 0}, cU10 = {0, 0, 0, 0}, cU11 = {0, 0, 0, 0};
    f4_t cW0 = {0, 0, 0, 0}, cW1 = {0, 0, 0, 0}, cG0 = {0, 0, 0, 0}, cG1 = {0, 0, 0, 0};
    {
      const int r1 = 16 + (l15 < 4 ? l15 : 3);  // clamp: rows 20..31 duplicate row 19 (ignored)
#pragma unroll
      for (int kf = 0; kf < 8; ++kf) {
        const int blk = (wv << 5) + (kf << 2) + lo4;  // 8-elem k-block index, 0..127
        const s8_t a0 = *(const s8_t*)&L.hnA[(l15 << 10) + ((blk ^ l15) << 3)];
        const s8_t a1 = *(const s8_t*)&L.hnA[(r1 << 10) + ((blk ^ (r1 & 15)) << 3)];
        const s8_t ax = *(const s8_t*)&L.xtA[l15 & 1][blk << 3];
        cU00 = MFMA(a0, BUh[0][kf], cU00);
        cU00 = MFMA(a0, BUl[0][kf], cU00);
        cU01 = MFMA(a0, BUh[1][kf], cU01);
        cU01 = MFMA(a0, BUl[1][kf], cU01);
        cU10 = MFMA(a1, BUh[0][kf], cU10);
        cU10 = MFMA(a1, BUl[0][kf], cU10);
        cU11 = MFMA(a1, BUh[1][kf], cU11);
        cU11 = MFMA(a1, BUl[1][kf], cU11);
        cW0 = MFMA(ax, BWh[0][kf], cW0);
        cW0 = MFMA(ax, BWl[0][kf], cW0);
        cW1 = MFMA(ax, BWh[1][kf], cW1);
        cW1 = MFMA(ax, BWl[1][kf], cW1);
        cG0 = MFMA(ax, a0, cG0);  // gate: xt(hi,lo rows) @ hn^T, B-frag == A-frag of hn
        cG1 = MFMA(ax, a1, cG1);
      }
    }

    // ---- cross-wave k-reduction, 2 LDS copies ----
    const int cp = wv & 1;
    if (wv < 2) {
#pragma unroll
      for (int q = 0; q < 4; ++q) {
        const int r = (lo4 << 2) + q;
        L.credU[cp][0][0][r][l15] = cU00[q];
        L.credU[cp][0][1][r][l15] = cU01[q];
        L.credU[cp][1][0][r][l15] = cU10[q];
        L.credU[cp][1][1][r][l15] = cU11[q];
      }
      if (lo4 == 0) {
        L.wxAcc[cp][0][l15] = cW0[0] + cW0[1];   // row0(hi)+row1(lo)
        L.wxAcc[cp][1][l15] = cW1[0] + cW1[1];
        L.gAcc[cp][0][l15] = cG0[0] + cG0[1];
        L.gAcc[cp][1][l15] = cG1[0] + cG1[1];
      }
    }
    __syncthreads();
    if (wv >= 2) {
#pragma unroll
      for (int q = 0; q < 4; ++q) {
        const int r = (lo4 << 2) + q;
        L.credU[cp][0][0][r][l15] += cU00[q];
        L.credU[cp][0][1][r][l15] += cU01[q];
        L.credU[cp][1][0][r][l15] += cU10[q];
        L.credU[cp][1][1][r][l15] += cU11[q];
      }
      if (lo4 == 0) {
        L.wxAcc[cp][0][l15] += cW0[0] + cW0[1];
        L.wxAcc[cp][1][l15] += cW1[0] + cW1[1];
        L.gAcc[cp][0][l15] += cG0[0] + cG0[1];
        L.gAcc[cp][1][l15] += cG1[0] + cG1[1];
      }
    }
    __syncthreads();

    // ---- gate + Wx finalize ----
    if (tid < NB) {
      const int mt = tid >> 4, ccc = tid & 15;
      const float pre = L.gAcc[0][mt][ccc] + L.gAcc[1][mt][ccc] +
                        KX[(size_t)(b * S + t) * NB + tid];
      L.gL[tid] = 1.0f / (1.0f + expf(-pre));
    } else if (tid >= 32 && tid < 64) {
      const int c = tid - 32;
      L.wxS[c] = L.wxAcc[0][c >> 4][c & 15] + L.wxAcc[1][c >> 4][c & 15];
    }
    __syncthreads();

    // ---- update: cand=tanh(hU+KV+Wx); h' = s*h + g*cand; publish bf16 ----
    if (tid < 160) {
      const int i = tid >> 3, c4 = (tid & 7) << 2;
      const int mt = i >> 4, r = i & 15, nt = c4 >> 4, ccc = c4 & 15;
      const f4_t sU = *(const f4_t*)&L.credU[0][mt][nt][r][ccc] +
                      *(const f4_t*)&L.credU[1][mt][nt][r][ccc];
      const f4_t kv = *(const f4_t*)&L.KVs[i][c4];
      const f4_t wx = *(const f4_t*)&L.wxS[c4];
      const f4_t oh = *(const f4_t*)&L.ownH[i][c4];
      const float s = L.sL[i], g = L.gL[i];
      f4_t hn;
      float sq = 0.f;
#pragma unroll
      for (int u = 0; u < 4; ++u) {
        const float cand = tanhf(sU[u] + kv[u] + wx[u]);
        const float hv = s * oh[u] + g * cand;
        hn[u] = hv;
        sq += hv * hv;
      }
      *(f4_t*)&L.ownH[i][c4] = hn;
      L.rowsq[i][tid & 7] = sq;
      const unsigned d0 = (unsigned)f2bf(hn[0]) | ((unsigned)f2bf(hn[1]) << 16);
      const unsigned d1 = (unsigned)f2bf(hn[2]) | ((unsigned)f2bf(hn[3]) << 16);
      unsigned* hb = Hbuf + (size_t)(nxt * B + b) * (NB * 512) + (i << 9) + (wg << 4) + (c4 >> 1);
      __hip_atomic_store(hb, d0, __ATOMIC_RELAXED, __HIP_MEMORY_SCOPE_AGENT);
      __hip_atomic_store(hb + 1, d1, __ATOMIC_RELAXED, __HIP_MEMORY_SCOPE_AGENT);
    }
    __syncthreads();
    if (tid < NB) {
      float sq = 0.f;
#pragma unroll
      for (int q = 0; q < 8; ++q) sq += L.rowsq[tid][q];
      __hip_atomic_store(NormP + ((size_t)(nxt * B + b) * NB + tid) * NWG + wg, sq,
                         __ATOMIC_RELAXED, __HIP_MEMORY_SCOPE_AGENT);
    }
    __syncthreads();

    // ---- per-batch barrier (monotone counter, device scope) ----
    if (tid == 0) {
      __hip_atomic_fetch_add(myctr, 1, __ATOMIC_RELEASE, __HIP_MEMORY_SCOPE_AGENT);
      const int tgt = NWG * (t + 1);
      while (__hip_atomic_load(myctr, __ATOMIC_RELAXED, __HIP_MEMORY_SCOPE_AGENT) < tgt)
        __builtin_amdgcn_s_sleep(1);
      (void)__hip_atomic_load(myctr, __ATOMIC_ACQUIRE, __HIP_MEMORY_SCOPE_AGENT);
    }
    __syncthreads();
  }

  // ---- final normalize + write output slice ----
  if (tid < 160) {
    const int i = tid >> 3, w4 = (tid & 7) << 2;
    float* np = NormP + ((size_t)(0 * B + b) * NB + i) * NWG + w4;
    float sq = 0.f;
#pragma unroll
    for (int q = 0; q < 4; ++q)
      sq += __hip_atomic_load(np + q, __ATOMIC_RELAXED, __HIP_MEMORY_SCOPE_AGENT);
    L.rowsq[i][tid & 7] = sq;
  }
  __syncthreads();
  if (tid < NB) {
    float sq = 0.f;
#pragma unroll
    for (int q = 0; q < 8; ++q) sq += L.rowsq[tid][q];
    L.sL[tid] = 1.0f / (sqrtf(sq) + EPS);
  }
  __syncthreads();
  if (tid < 160) {
    const int i = tid >> 3, c4 = (tid & 7) << 2;
    const float s = L.sL[i];
    const f4_t oh = *(const f4_t*)&L.ownH[i][c4];
    f4_t o;
#pragma unroll
    for (int u = 0; u < 4; ++u) o[u] = s * oh[u];
    *(f4_t*)(out + (size_t)b * NB * D + (size_t)i * D + (wg << 5) + c4) = o;
  }
}

}  // namespace

extern "C" void kernel_launch(void* const* d_in, const int* in_sizes, int n_in,
                              void* d_out, int out_size, void* d_ws, size_t ws_size,
                              hipStream_t stream) {
  const float* e = (const float*)d_in[0];
  const float* m = (const float*)d_in[1];
  const float* state = (const float*)d_in[2];
  const float* U = (const float*)d_in[3];
  const float* V = (const float*)d_in[4];
  const float* W = (const float*)d_in[5];
  const float* keys = (const float*)d_in[6];
  float* out = (float*)d_out;
  char* ws = (char*)d_ws;

  unsigned* Hbuf = (unsigned*)(ws + OFF_HBUF);
  float* NormP = (float*)(ws + OFF_NORM);
  int* ctr = (int*)(ws + OFF_CTR);
  float* KV = (float*)(ws + OFF_KV);
  float* KX = (float*)(ws + OFF_KX);
  unsigned short* Uhi = (unsigned short*)(ws + OFF_UHI);
  unsigned short* Ulo = (unsigned short*)(ws + OFF_ULO);
  unsigned short* Whi = (unsigned short*)(ws + OFF_WHI);
  unsigned short* Wlo = (unsigned short*)(ws + OFF_WLO);

  k_convert<<<512, 256, 0, stream>>>(U, W, Uhi, Ulo, Whi, Wlo);
  k_kv<<<16, 256, 0, stream>>>(keys, V, KV);
  k_kx<<<B * S, 256, 0, stream>>>(e, m, keys, KX);
  k_state<<<341, 256, 0, stream>>>(state, Hbuf, NormP, ctr);
  k_rnn<<<256, 256, 0, stream>>>(e, m, state, KX, KV, Uhi, Ulo, Whi, Wlo,
                                 Hbuf, NormP, ctr, out);
}

// Round 2
// 26407.776 us; speedup vs baseline: 1.4323x; 1.4323x over previous
//
#include <hip/hip_runtime.h>
#include <cstdint>
#include <cstddef>

namespace {

constexpr int D   = 1024;
constexpr int NB  = 20;
constexpr int B   = 8;
constexpr int S   = 2048;
constexpr int NWG = 32;      // workgroups cooperating per batch
constexpr float EPS = 1e-8f;

typedef __attribute__((ext_vector_type(4))) float f4_t;
typedef __attribute__((ext_vector_type(8))) short s8_t;
typedef __attribute__((ext_vector_type(4))) unsigned u4_t;
typedef __attribute__((ext_vector_type(2))) unsigned u2_t;

__device__ __forceinline__ unsigned short f2bf(float f) {
  unsigned u = __float_as_uint(f);
  u += 0x7fffu + ((u >> 16) & 1u);     // RNE
  return (unsigned short)(u >> 16);
}
__device__ __forceinline__ float bf2f(unsigned short h) {
  return __uint_as_float(((unsigned)h) << 16);
}

#define MFMA(a, b, c) __builtin_amdgcn_mfma_f32_16x16x32_bf16((a), (b), (c), 0, 0, 0)

// ---- workspace layout (bytes) ----
constexpr size_t OFF_HBUF = 0;                                   // u32 [2][B][NB][512]  (bf16 pairs)
constexpr size_t OFF_NORM = OFF_HBUF + 2ull * B * NB * 512 * 4;  // f32 [2][B][NB][NWG]
constexpr size_t OFF_CTR  = OFF_NORM + 2ull * B * NB * NWG * 4;  // i32 [B][16]
constexpr size_t OFF_KV   = OFF_CTR + (size_t)B * 16 * 4;        // f32 [NB][D]
constexpr size_t OFF_KX   = OFF_KV + (size_t)NB * D * 4;         // f32 [B*S][NB]
constexpr size_t OFF_UHI  = OFF_KX + (size_t)B * S * NB * 4;     // u16 [D][D]
constexpr size_t OFF_ULO  = OFF_UHI + (size_t)D * D * 2;
constexpr size_t OFF_WHI  = OFF_ULO + (size_t)D * D * 2;
constexpr size_t OFF_WLO  = OFF_WHI + (size_t)D * D * 2;

// ---------------- init kernels ----------------

__global__ void k_convert(const float* __restrict__ U, const float* __restrict__ W,
                          unsigned short* __restrict__ Uhi, unsigned short* __restrict__ Ulo,
                          unsigned short* __restrict__ Whi, unsigned short* __restrict__ Wlo) {
  const int n = D * D;
  for (int i = blockIdx.x * blockDim.x + threadIdx.x; i < n; i += gridDim.x * blockDim.x) {
    float u = U[i];
    unsigned short h = f2bf(u);
    Uhi[i] = h;
    Ulo[i] = f2bf(u - bf2f(h));
    float w = W[i];
    h = f2bf(w);
    Whi[i] = h;
    Wlo[i] = f2bf(w - bf2f(h));
  }
}

// KV[i][j] = keys[i] . V[j]
__global__ void k_kv(const float* __restrict__ keys, const float* __restrict__ V,
                     float* __restrict__ KV) {
  const int tid = threadIdx.x;
  const int j = blockIdx.x * 64 + (tid >> 2);
  const int kq = tid & 3;
  const f4_t* v4 = (const f4_t*)(V + (size_t)j * D + kq * 256);
  const f4_t* k4base = (const f4_t*)keys;
  float acc[NB];
#pragma unroll
  for (int i = 0; i < NB; ++i) acc[i] = 0.f;
  for (int q = 0; q < 64; ++q) {
    const f4_t v = v4[q];
#pragma unroll
    for (int i = 0; i < NB; ++i) {
      const f4_t kk = k4base[i * 256 + kq * 64 + q];
      acc[i] += kk[0] * v[0] + kk[1] * v[1] + kk[2] * v[2] + kk[3] * v[3];
    }
  }
#pragma unroll
  for (int i = 0; i < NB; ++i) {
    float s = acc[i];
    s += __shfl_xor(s, 1);
    s += __shfl_xor(s, 2);
    if (kq == 0) KV[(size_t)i * D + j] = s;
  }
}

// KX[bt][i] = keys[i] . (e[bt]+m[bt])
__global__ void k_kx(const float* __restrict__ e, const float* __restrict__ m,
                     const float* __restrict__ keys, float* __restrict__ KX) {
  __shared__ f4_t xs[256];
  __shared__ float part[NB][8];
  const int bt = blockIdx.x, tid = threadIdx.x;
  xs[tid] = ((const f4_t*)e)[(size_t)bt * 256 + tid] + ((const f4_t*)m)[(size_t)bt * 256 + tid];
  __syncthreads();
  if (tid < 160) {
    const int i = tid >> 3, s8 = tid & 7;
    float acc = 0.f;
    const f4_t* k4 = (const f4_t*)keys + i * 256 + s8 * 32;
    for (int q = 0; q < 32; ++q) {
      const f4_t kk = k4[q];
      const f4_t xx = xs[s8 * 32 + q];
      acc += kk[0] * xx[0] + kk[1] * xx[1] + kk[2] * xx[2] + kk[3] * xx[3];
    }
    part[i][s8] = acc;
  }
  __syncthreads();
  if (tid < NB) {
    float s = 0.f;
#pragma unroll
    for (int q = 0; q < 8; ++q) s += part[tid][q];
    KX[(size_t)bt * NB + tid] = s;
  }
}

__global__ void k_state(const float* __restrict__ state, unsigned* __restrict__ Hbuf,
                        float* __restrict__ NormP, int* __restrict__ ctr) {
  const int idx = blockIdx.x * 256 + threadIdx.x;
  if (idx < B * NB * 512) {
    const int r = idx % (NB * 512);
    const int i = r >> 9, d2 = (r & 511) << 1;
    const unsigned short a = f2bf(state[i * D + d2]);
    const unsigned short c = f2bf(state[i * D + d2 + 1]);
    Hbuf[idx] = (unsigned)a | ((unsigned)c << 16);
  }
  const int j = idx - B * NB * 512;
  if (j >= 0 && j < B * NB * NWG) NormP[j] = 1.0f / 32.0f;  // sumsq=1 -> s=1 exactly
  const int q = idx - B * NB * 512 - B * NB * NWG;
  if (q >= 0 && q < B * 16) ctr[q] = 0;
}

// ---------------- persistent recurrence kernel ----------------

struct __align__(16) LdsT {
  unsigned short xtA[2][D];        // rows: 0=xt_hi, 1=xt_lo (bf16)
  float credU[2][2][2][16][20];    // [copy][mt][nt][row][col pad20]
  float wxAcc[2][2][16];           // [copy][nt][col]
  float gAcc[2][2][16];            // [copy][mt][col]
  float KVs[NB][32];
  float ownH[NB][32];              // fp32 unnormalized h slice (exact path)
  float sL[NB];
  float gL[NB];
  float wxS[32];
  float rowsq[NB][8];
  unsigned short hnA[NB * D];      // bf16 RAW (unnormalized) h, k-block swizzled by (row&15)
};

__launch_bounds__(256, 1)
__global__ void k_rnn(const float* __restrict__ e, const float* __restrict__ m,
                      const float* __restrict__ state,
                      const float* __restrict__ KX, const float* __restrict__ KV,
                      const unsigned short* __restrict__ Uhi, const unsigned short* __restrict__ Ulo,
                      const unsigned short* __restrict__ Whi, const unsigned short* __restrict__ Wlo,
                      unsigned* __restrict__ Hbuf, float* __restrict__ NormP,
                      int* __restrict__ ctr, float* __restrict__ out) {
  __shared__ LdsT L;
  const int tid = threadIdx.x;
  const int b = blockIdx.x & 7;    // consecutive blocks -> different XCDs: batch stays XCD-local (perf heuristic only)
  const int wg = blockIdx.x >> 3;  // column-slice id, owns cols [wg*32, wg*32+32)
  const int wv = tid >> 6;
  const int ln = tid & 63;
  const int l15 = ln & 15;
  const int lo4 = ln >> 4;

  // resident B-fragments: U and W column slices, bf16 hi/lo, this wave's k-chunk [wv*256, wv*256+256)
  s8_t BUh[2][8], BUl[2][8], BWh[2][8], BWl[2][8];
  {
    const int rowb = (wg << 5) + l15;
#pragma unroll
    for (int nt = 0; nt < 2; ++nt)
#pragma unroll
      for (int kf = 0; kf < 8; ++kf) {
        const size_t off = (size_t)(rowb + nt * 16) * D + (wv << 8) + (kf << 5) + (lo4 << 3);
        BUh[nt][kf] = *(const s8_t*)(Uhi + off);
        BUl[nt][kf] = *(const s8_t*)(Ulo + off);
        BWh[nt][kf] = *(const s8_t*)(Whi + off);
        BWl[nt][kf] = *(const s8_t*)(Wlo + off);
      }
  }
  if (tid < 160) {
    const int i = tid >> 3, c4 = (tid & 7) << 2;
    *(f4_t*)&L.ownH[i][c4] = *(const f4_t*)(state + (size_t)i * D + (wg << 5) + c4);
    *(f4_t*)&L.KVs[i][c4] = *(const f4_t*)(KV + (size_t)i * D + (wg << 5) + c4);
  }
  __syncthreads();

  int* const myctr = ctr + b * 16;

  // prefetch e/m for step 0
  f4_t ev = ((const f4_t*)e)[(size_t)(b * S) * 256 + tid];
  f4_t mv = ((const f4_t*)m)[(size_t)(b * S) * 256 + tid];

  for (int t = 0; t < S; ++t) {
    const int cur = t & 1, nxt = cur ^ 1;

    // ---- gather: raw bf16 h via plain vectorized loads (acquire at prior barrier
    //      makes them coherent), plus NormP partials (plain) ----
    u4_t hv[10];
    {
      const u4_t* hb4 = (const u4_t*)(Hbuf + (size_t)(cur * B + b) * (NB * 512));
#pragma unroll
      for (int j = 0; j < 10; ++j) hv[j] = hb4[j * 256 + tid];
    }
    f4_t npv = {0, 0, 0, 0};
    if (tid < 160) {
      const int i = tid >> 3, w4 = (tid & 7) << 2;
      npv = *(const f4_t*)(NormP + ((size_t)(cur * B + b) * NB + i) * NWG + w4);
    }

    // ---- build xt (hi/lo bf16) from prefetched regs ----
    {
      const f4_t x = ev + mv;
      const unsigned short h0 = f2bf(x[0]), h1 = f2bf(x[1]), h2 = f2bf(x[2]), h3 = f2bf(x[3]);
      const unsigned short u0 = f2bf(x[0] - bf2f(h0)), u1 = f2bf(x[1] - bf2f(h1));
      const unsigned short u2 = f2bf(x[2] - bf2f(h2)), u3 = f2bf(x[3] - bf2f(h3));
      const int kp = tid << 2;
      *(unsigned*)&L.xtA[0][kp] = (unsigned)h0 | ((unsigned)h1 << 16);
      *(unsigned*)&L.xtA[0][kp + 2] = (unsigned)h2 | ((unsigned)h3 << 16);
      *(unsigned*)&L.xtA[1][kp] = (unsigned)u0 | ((unsigned)u1 << 16);
      *(unsigned*)&L.xtA[1][kp + 2] = (unsigned)u2 | ((unsigned)u3 << 16);
    }

    // ---- store raw h dwords to LDS, swizzled; one uint4 == one 8-elem swizzle block ----
    {
      const int blkk = tid & 127;
#pragma unroll
      for (int j = 0; j < 10; ++j) {
        const int i = 2 * j + (tid >> 7);
        *(u4_t*)&L.hnA[(i << 10) + ((blkk ^ (i & 15)) << 3)] = hv[j];
      }
    }
    __syncthreads();

    // ---- MFMA on RAW h: h@U^T (split U), Wx (xt hi/lo rows, split W), gate h.xt ----
    f4_t cU00 = {0, 0, 0, 0}, cU01 = {0, 0, 0, 0}, cU10 = {0, 0, 0, 0}, cU11 = {0, 0, 0, 0};
    f4_t cW0 = {0, 0, 0, 0}, cW1 = {0, 0, 0, 0}, cG0 = {0, 0, 0, 0}, cG1 = {0, 0, 0, 0};
    {
      const int r1 = 16 + (l15 < 4 ? l15 : 3);  // clamp: rows 20..31 duplicate row 19 (ignored)
#pragma unroll
      for (int kf = 0; kf < 8; ++kf) {
        const int blk = (wv << 5) + (kf << 2) + lo4;  // 8-elem k-block index, 0..127
        const s8_t a0 = *(const s8_t*)&L.hnA[(l15 << 10) + ((blk ^ l15) << 3)];
        const s8_t a1 = *(const s8_t*)&L.hnA[(r1 << 10) + ((blk ^ (r1 & 15)) << 3)];
        const s8_t ax = *(const s8_t*)&L.xtA[l15 & 1][blk << 3];
        cU00 = MFMA(a0, BUh[0][kf], cU00);
        cU00 = MFMA(a0, BUl[0][kf], cU00);
        cU01 = MFMA(a0, BUh[1][kf], cU01);
        cU01 = MFMA(a0, BUl[1][kf], cU01);
        cU10 = MFMA(a1, BUh[0][kf], cU10);
        cU10 = MFMA(a1, BUl[0][kf], cU10);
        cU11 = MFMA(a1, BUh[1][kf], cU11);
        cU11 = MFMA(a1, BUl[1][kf], cU11);
        cW0 = MFMA(ax, BWh[0][kf], cW0);
        cW0 = MFMA(ax, BWl[0][kf], cW0);
        cW1 = MFMA(ax, BWh[1][kf], cW1);
        cW1 = MFMA(ax, BWl[1][kf], cW1);
        cG0 = MFMA(ax, a0, cG0);  // gate: xt(hi,lo rows) @ h_raw^T
        cG1 = MFMA(ax, a1, cG1);
      }
    }

    // ---- cross-wave k-reduction, 2 LDS copies; NormP partials -> rowsq ----
    const int cp = wv & 1;
    if (wv < 2) {
#pragma unroll
      for (int q = 0; q < 4; ++q) {
        const int r = (lo4 << 2) + q;
        L.credU[cp][0][0][r][l15] = cU00[q];
        L.credU[cp][0][1][r][l15] = cU01[q];
        L.credU[cp][1][0][r][l15] = cU10[q];
        L.credU[cp][1][1][r][l15] = cU11[q];
      }
      if (lo4 == 0) {
        L.wxAcc[cp][0][l15] = cW0[0] + cW0[1];   // row0(hi)+row1(lo)
        L.wxAcc[cp][1][l15] = cW1[0] + cW1[1];
        L.gAcc[cp][0][l15] = cG0[0] + cG0[1];
        L.gAcc[cp][1][l15] = cG1[0] + cG1[1];
      }
    }
    if (tid < 160) {
      L.rowsq[tid >> 3][tid & 7] = npv[0] + npv[1] + npv[2] + npv[3];
    }
    __syncthreads();
    if (wv >= 2) {
#pragma unroll
      for (int q = 0; q < 4; ++q) {
        const int r = (lo4 << 2) + q;
        L.credU[cp][0][0][r][l15] += cU00[q];
        L.credU[cp][0][1][r][l15] += cU01[q];
        L.credU[cp][1][0][r][l15] += cU10[q];
        L.credU[cp][1][1][r][l15] += cU11[q];
      }
      if (lo4 == 0) {
        L.wxAcc[cp][0][l15] += cW0[0] + cW0[1];
        L.wxAcc[cp][1][l15] += cW1[0] + cW1[1];
        L.gAcc[cp][0][l15] += cG0[0] + cG0[1];
        L.gAcc[cp][1][l15] += cG1[0] + cG1[1];
      }
    }
    if (tid < NB) {   // wave 0 computes sL concurrently with waves 2,3 accumulating
      float sq = 0.f;
#pragma unroll
      for (int q = 0; q < 8; ++q) sq += L.rowsq[tid][q];
      L.sL[tid] = 1.0f / (sqrtf(sq) + EPS);
    }
    __syncthreads();

    // ---- gate + Wx finalize (deferred scale: pre = s * (h_raw . xt) + kx) ----
    if (tid < NB) {
      const int mt = tid >> 4, ccc = tid & 15;
      const float pre = L.sL[tid] * (L.gAcc[0][mt][ccc] + L.gAcc[1][mt][ccc]) +
                        KX[(size_t)(b * S + t) * NB + tid];
      L.gL[tid] = 1.0f / (1.0f + expf(-pre));
    } else if (tid >= 32 && tid < 64) {
      const int c = tid - 32;
      L.wxS[c] = L.wxAcc[0][c >> 4][c & 15] + L.wxAcc[1][c >> 4][c & 15];
    }
    __syncthreads();

    // ---- update: cand=tanh(s*hU_raw+KV+Wx); h' = s*h + g*cand; publish bf16 (plain) ----
    if (tid < 160) {
      const int i = tid >> 3, c4 = (tid & 7) << 2;
      const int mt = i >> 4, r = i & 15, nt = c4 >> 4, ccc = c4 & 15;
      const f4_t sU = *(const f4_t*)&L.credU[0][mt][nt][r][ccc] +
                      *(const f4_t*)&L.credU[1][mt][nt][r][ccc];
      const f4_t kv = *(const f4_t*)&L.KVs[i][c4];
      const f4_t wx = *(const f4_t*)&L.wxS[c4];
      const f4_t oh = *(const f4_t*)&L.ownH[i][c4];
      const float s = L.sL[i], g = L.gL[i];
      f4_t hn;
      float sq = 0.f;
#pragma unroll
      for (int u = 0; u < 4; ++u) {
        const float cand = tanhf(s * sU[u] + kv[u] + wx[u]);
        const float hv2 = s * oh[u] + g * cand;
        hn[u] = hv2;
        sq += hv2 * hv2;
      }
      *(f4_t*)&L.ownH[i][c4] = hn;
      L.rowsq[i][tid & 7] = sq;
      u2_t dd;
      dd[0] = (unsigned)f2bf(hn[0]) | ((unsigned)f2bf(hn[1]) << 16);
      dd[1] = (unsigned)f2bf(hn[2]) | ((unsigned)f2bf(hn[3]) << 16);
      unsigned* hb = Hbuf + (size_t)(nxt * B + b) * (NB * 512) + (i << 9) + (wg << 4) + (c4 >> 1);
      *(u2_t*)hb = dd;
    }
    __syncthreads();
    if (tid < NB) {
      float sq = 0.f;
#pragma unroll
      for (int q = 0; q < 8; ++q) sq += L.rowsq[tid][q];
      NormP[((size_t)(nxt * B + b) * NB + tid) * NWG + wg] = sq;
    }

    // ---- per-batch barrier (monotone counter). Release add covers all prior
    //      plain stores (post-__syncthreads); acquire load invalidates caches. ----
    if (tid == 0) {
      __hip_atomic_fetch_add(myctr, 1, __ATOMIC_RELEASE, __HIP_MEMORY_SCOPE_AGENT);
    }
    // prefetch e/m for t+1 while the barrier settles (issued after the release add
    // so tid0's vmcnt drain before the add doesn't wait on them)
    if (t + 1 < S) {
      ev = ((const f4_t*)e)[(size_t)(b * S + t + 1) * 256 + tid];
      mv = ((const f4_t*)m)[(size_t)(b * S + t + 1) * 256 + tid];
    }
    if (tid == 0) {
      const int tgt = NWG * (t + 1);
      while (__hip_atomic_load(myctr, __ATOMIC_RELAXED, __HIP_MEMORY_SCOPE_AGENT) < tgt)
        __builtin_amdgcn_s_sleep(8);
      (void)__hip_atomic_load(myctr, __ATOMIC_ACQUIRE, __HIP_MEMORY_SCOPE_AGENT);
    }
    __syncthreads();
  }

  // ---- final normalize + write output slice (NormP buffer 0 = written at t=S-1) ----
  if (tid < 160) {
    const int i = tid >> 3, w4 = (tid & 7) << 2;
    const f4_t npv = *(const f4_t*)(NormP + ((size_t)(0 * B + b) * NB + i) * NWG + w4);
    L.rowsq[i][tid & 7] = npv[0] + npv[1] + npv[2] + npv[3];
  }
  __syncthreads();
  if (tid < NB) {
    float sq = 0.f;
#pragma unroll
    for (int q = 0; q < 8; ++q) sq += L.rowsq[tid][q];
    L.sL[tid] = 1.0f / (sqrtf(sq) + EPS);
  }
  __syncthreads();
  if (tid < 160) {
    const int i = tid >> 3, c4 = (tid & 7) << 2;
    const float s = L.sL[i];
    const f4_t oh = *(const f4_t*)&L.ownH[i][c4];
    f4_t o;
#pragma unroll
    for (int u = 0; u < 4; ++u) o[u] = s * oh[u];
    *(f4_t*)(out + (size_t)b * NB * D + (size_t)i * D + (wg << 5) + c4) = o;
  }
}

}  // namespace

extern "C" void kernel_launch(void* const* d_in, const int* in_sizes, int n_in,
                              void* d_out, int out_size, void* d_ws, size_t ws_size,
                              hipStream_t stream) {
  const float* e = (const float*)d_in[0];
  const float* m = (const float*)d_in[1];
  const float* state = (const float*)d_in[2];
  const float* U = (const float*)d_in[3];
  const float* V = (const float*)d_in[4];
  const float* W = (const float*)d_in[5];
  const float* keys = (const float*)d_in[6];
  float* out = (float*)d_out;
  char* ws = (char*)d_ws;

  unsigned* Hbuf = (unsigned*)(ws + OFF_HBUF);
  float* NormP = (float*)(ws + OFF_NORM);
  int* ctr = (int*)(ws + OFF_CTR);
  float* KV = (float*)(ws + OFF_KV);
  float* KX = (float*)(ws + OFF_KX);
  unsigned short* Uhi = (unsigned short*)(ws + OFF_UHI);
  unsigned short* Ulo = (unsigned short*)(ws + OFF_ULO);
  unsigned short* Whi = (unsigned short*)(ws + OFF_WHI);
  unsigned short* Wlo = (unsigned short*)(ws + OFF_WLO);

  k_convert<<<512, 256, 0, stream>>>(U, W, Uhi, Ulo, Whi, Wlo);
  k_kv<<<16, 256, 0, stream>>>(keys, V, KV);
  k_kx<<<B * S, 256, 0, stream>>>(e, m, keys, KX);
  k_state<<<341, 256, 0, stream>>>(state, Hbuf, NormP, ctr);
  k_rnn<<<256, 256, 0, stream>>>(e, m, state, KX, KV, Uhi, Ulo, Whi, Wlo,
                                 Hbuf, NormP, ctr, out);
}

// Round 4
// 22323.407 us; speedup vs baseline: 1.6944x; 1.1830x over previous
//
#include <hip/hip_runtime.h>
#include <cstdint>
#include <cstddef>

namespace {

constexpr int D   = 1024;
constexpr int NB  = 20;
constexpr int B   = 8;
constexpr int S   = 2048;
constexpr int NWG = 32;      // workgroups cooperating per batch
constexpr float EPS = 1e-8f;

typedef __attribute__((ext_vector_type(4))) float f4_t;
typedef __attribute__((ext_vector_type(8))) short s8_t;
typedef unsigned long long u64_t;

__device__ __forceinline__ unsigned short f2bf(float f) {
  unsigned u = __float_as_uint(f);
  u += 0x7fffu + ((u >> 16) & 1u);     // RNE
  return (unsigned short)(u >> 16);
}
__device__ __forceinline__ float bf2f(unsigned short h) {
  return __uint_as_float(((unsigned)h) << 16);
}
__device__ __forceinline__ float u64lo(u64_t x) { return __uint_as_float((unsigned)x); }
__device__ __forceinline__ float u64hi(u64_t x) { return __uint_as_float((unsigned)(x >> 32)); }

#define MFMA(a, b, c) __builtin_amdgcn_mfma_f32_16x16x32_bf16((a), (b), (c), 0, 0, 0)
#define ALOAD64(p) __hip_atomic_load((p), __ATOMIC_RELAXED, __HIP_MEMORY_SCOPE_AGENT)
#define ASTORE64(p, v) __hip_atomic_store((p), (v), __ATOMIC_RELAXED, __HIP_MEMORY_SCOPE_AGENT)

// ---- workspace layout (bytes) ----
constexpr size_t OFF_HBUF = 0;                                   // u32 [2][B][NB][512]  (bf16 pairs)
constexpr size_t OFF_NORM = OFF_HBUF + 2ull * B * NB * 512 * 4;  // f32 [2][B][NB][NWG]
constexpr size_t OFF_CTR  = OFF_NORM + 2ull * B * NB * NWG * 4;  // i32 [B][16]
constexpr size_t OFF_KV   = OFF_CTR + (size_t)B * 16 * 4;        // f32 [NB][D]
constexpr size_t OFF_KX   = OFF_KV + (size_t)NB * D * 4;         // f32 [B*S][NB]
constexpr size_t OFF_UHI  = OFF_KX + (size_t)B * S * NB * 4;     // u16 [D][D]
constexpr size_t OFF_ULO  = OFF_UHI + (size_t)D * D * 2;
constexpr size_t OFF_WHI  = OFF_ULO + (size_t)D * D * 2;
constexpr size_t OFF_WLO  = OFF_WHI + (size_t)D * D * 2;

// ---------------- init kernels ----------------

__global__ void k_convert(const float* __restrict__ U, const float* __restrict__ W,
                          unsigned short* __restrict__ Uhi, unsigned short* __restrict__ Ulo,
                          unsigned short* __restrict__ Whi, unsigned short* __restrict__ Wlo) {
  const int n = D * D;
  for (int i = blockIdx.x * blockDim.x + threadIdx.x; i < n; i += gridDim.x * blockDim.x) {
    float u = U[i];
    unsigned short h = f2bf(u);
    Uhi[i] = h;
    Ulo[i] = f2bf(u - bf2f(h));
    float w = W[i];
    h = f2bf(w);
    Whi[i] = h;
    Wlo[i] = f2bf(w - bf2f(h));
  }
}

// KV[i][j] = keys[i] . V[j]
__global__ void k_kv(const float* __restrict__ keys, const float* __restrict__ V,
                     float* __restrict__ KV) {
  const int tid = threadIdx.x;
  const int j = blockIdx.x * 64 + (tid >> 2);
  const int kq = tid & 3;
  const f4_t* v4 = (const f4_t*)(V + (size_t)j * D + kq * 256);
  const f4_t* k4base = (const f4_t*)keys;
  float acc[NB];
#pragma unroll
  for (int i = 0; i < NB; ++i) acc[i] = 0.f;
  for (int q = 0; q < 64; ++q) {
    const f4_t v = v4[q];
#pragma unroll
    for (int i = 0; i < NB; ++i) {
      const f4_t kk = k4base[i * 256 + kq * 64 + q];
      acc[i] += kk[0] * v[0] + kk[1] * v[1] + kk[2] * v[2] + kk[3] * v[3];
    }
  }
#pragma unroll
  for (int i = 0; i < NB; ++i) {
    float s = acc[i];
    s += __shfl_xor(s, 1);
    s += __shfl_xor(s, 2);
    if (kq == 0) KV[(size_t)i * D + j] = s;
  }
}

// KX[bt][i] = keys[i] . (e[bt]+m[bt])
__global__ void k_kx(const float* __restrict__ e, const float* __restrict__ m,
                     const float* __restrict__ keys, float* __restrict__ KX) {
  __shared__ f4_t xs[256];
  __shared__ float part[NB][8];
  const int bt = blockIdx.x, tid = threadIdx.x;
  xs[tid] = ((const f4_t*)e)[(size_t)bt * 256 + tid] + ((const f4_t*)m)[(size_t)bt * 256 + tid];
  __syncthreads();
  if (tid < 160) {
    const int i = tid >> 3, s8 = tid & 7;
    float acc = 0.f;
    const f4_t* k4 = (const f4_t*)keys + i * 256 + s8 * 32;
    for (int q = 0; q < 32; ++q) {
      const f4_t kk = k4[q];
      const f4_t xx = xs[s8 * 32 + q];
      acc += kk[0] * xx[0] + kk[1] * xx[1] + kk[2] * xx[2] + kk[3] * xx[3];
    }
    part[i][s8] = acc;
  }
  __syncthreads();
  if (tid < NB) {
    float s = 0.f;
#pragma unroll
    for (int q = 0; q < 8; ++q) s += part[tid][q];
    KX[(size_t)bt * NB + tid] = s;
  }
}

__global__ void k_state(const float* __restrict__ state, unsigned* __restrict__ Hbuf,
                        float* __restrict__ NormP, int* __restrict__ ctr) {
  const int idx = blockIdx.x * 256 + threadIdx.x;
  if (idx < B * NB * 512) {
    const int r = idx % (NB * 512);
    const int i = r >> 9, d2 = (r & 511) << 1;
    const unsigned short a = f2bf(state[i * D + d2]);
    const unsigned short c = f2bf(state[i * D + d2 + 1]);
    Hbuf[idx] = (unsigned)a | ((unsigned)c << 16);
  }
  const int j = idx - B * NB * 512;
  if (j >= 0 && j < B * NB * NWG) NormP[j] = 1.0f / 32.0f;  // sumsq=1 -> s=1 exactly
  const int q = idx - B * NB * 512 - B * NB * NWG;
  if (q >= 0 && q < B * 16) ctr[q] = 0;
}

// ---------------- persistent recurrence kernel ----------------
// 128 blocks; block = (pair p of batches {2p,2p+1}) x (column slice wg of 32).
// Per t, the block runs phase A (batch 2p) then phase B (batch 2p+1); each
// batch's inter-WG barrier is hidden behind the other batch's compute phase.

struct __align__(16) LdsT {
  unsigned short xtA[2][D];        // shared per-phase: xt hi/lo rows (bf16)
  float credU[4][2][2][16][20];    // per-wave copies [wv][mt][nt][row][col pad20]
  float wxAcc[4][2][16];           // [wv][nt][col]
  float gAcc[4][2][16];            // [wv][mt][col]
  float KVs[NB][32];               // batch-independent
  float ownH[2][NB][32];           // per-batch fp32 unnormalized h slice
  float sL[NB];
  float gL[NB];
  float wxS[32];
  float rowsq[NB][8];
  unsigned short hnA[NB * 1024];   // shared per-phase: raw bf16 h, swizzled
};

__launch_bounds__(256, 1)
__global__ void k_rnn(const float* __restrict__ e, const float* __restrict__ m,
                      const float* __restrict__ state,
                      const float* __restrict__ KX, const float* __restrict__ KV,
                      const unsigned short* __restrict__ Uhi, const unsigned short* __restrict__ Ulo,
                      const unsigned short* __restrict__ Whi, const unsigned short* __restrict__ Wlo,
                      unsigned* __restrict__ Hbuf, float* __restrict__ NormP,
                      int* __restrict__ ctr, float* __restrict__ out) {
  __shared__ LdsT L;
  const int tid = threadIdx.x;
  // blockIdx bits: [0]=wg-high, [1:2]=pair, [3:6]=wg-low. With i%8 XCD round-robin
  // (heuristic only), pair p lands on XCDs {2p,2p+1} -> exchange stays local-ish.
  const int pair = (blockIdx.x >> 1) & 3;
  const int bA = pair << 1;
  const int wg = ((blockIdx.x & 1) << 4) | (blockIdx.x >> 3);  // 0..31 column slice
  const int wv = tid >> 6;
  const int ln = tid & 63;
  const int l15 = ln & 15;
  const int lo4 = ln >> 4;

  // resident B-fragments: U and W column slices, bf16 hi/lo, this wave's k-chunk.
  // Shared by both batches of the pair (same columns).
  s8_t BUh[2][8], BUl[2][8], BWh[2][8], BWl[2][8];
  {
    const int rowb = (wg << 5) + l15;
#pragma unroll
    for (int nt = 0; nt < 2; ++nt)
#pragma unroll
      for (int kf = 0; kf < 8; ++kf) {
        const size_t off = (size_t)(rowb + nt * 16) * D + (wv << 8) + (kf << 5) + (lo4 << 3);
        BUh[nt][kf] = *(const s8_t*)(Uhi + off);
        BUl[nt][kf] = *(const s8_t*)(Ulo + off);
        BWh[nt][kf] = *(const s8_t*)(Whi + off);
        BWl[nt][kf] = *(const s8_t*)(Wlo + off);
      }
  }
  if (tid < 160) {
    const int i = tid >> 3, c4 = (tid & 7) << 2;
    const f4_t h0 = *(const f4_t*)(state + (size_t)i * D + (wg << 5) + c4);
    *(f4_t*)&L.ownH[0][i][c4] = h0;
    *(f4_t*)&L.ownH[1][i][c4] = h0;   // shared initial state across batches
    *(f4_t*)&L.KVs[i][c4] = *(const f4_t*)(KV + (size_t)i * D + (wg << 5) + c4);
  }
  __syncthreads();

  // prefetch e/m for step 0, both batches
  f4_t evv[2], mvv[2];
#pragma unroll
  for (int ph = 0; ph < 2; ++ph) {
    evv[ph] = ((const f4_t*)e)[(size_t)((bA + ph) * S) * 256 + tid];
    mvv[ph] = ((const f4_t*)m)[(size_t)((bA + ph) * S) * 256 + tid];
  }

  for (int t = 0; t < S; ++t) {
    const int cur = t & 1, nxt = cur ^ 1;
#pragma unroll
    for (int ph = 0; ph < 2; ++ph) {
      const int b = bA + ph;
      int* const myctr = ctr + b * 16;

      // ---- poll: partners released h(t) one full phase ago (slack = other phase) ----
      if (tid == 0) {
        const int tgt = NWG * t;
        while (__hip_atomic_load(myctr, __ATOMIC_RELAXED, __HIP_MEMORY_SCOPE_AGENT) < tgt)
          __builtin_amdgcn_s_sleep(1);
      }
      __syncthreads();

      // ---- gather: coherent (sc0sc1) u64 loads straight from LLC; no acquire-inv ----
      u64_t hv[20];
      {
        u64_t* hb8 = (u64_t*)Hbuf + (size_t)(cur * B + b) * (NB * 256);
#pragma unroll
        for (int j = 0; j < 20; ++j) hv[j] = ALOAD64(hb8 + j * 256 + tid);
      }
      float np4 = 0.f;
      if (tid < 160) {
        const int i = tid >> 3;
        u64_t* np8 = (u64_t*)NormP + ((size_t)(cur * B + b) * NB + i) * 16 + ((tid & 7) << 1);
        const u64_t x0 = ALOAD64(np8);
        const u64_t x1 = ALOAD64(np8 + 1);
        np4 = u64lo(x0) + u64hi(x0) + u64lo(x1) + u64hi(x1);
      }
      float kx = 0.f;
      if (tid < NB) kx = KX[(size_t)(b * S + t) * NB + tid];

      // ---- build xt (hi/lo bf16) from prefetched regs ----
      {
        const f4_t x = evv[ph] + mvv[ph];
        const unsigned short h0 = f2bf(x[0]), h1 = f2bf(x[1]), h2 = f2bf(x[2]), h3 = f2bf(x[3]);
        const unsigned short u0 = f2bf(x[0] - bf2f(h0)), u1 = f2bf(x[1] - bf2f(h1));
        const unsigned short u2 = f2bf(x[2] - bf2f(h2)), u3 = f2bf(x[3] - bf2f(h3));
        const int kp = tid << 2;
        *(unsigned*)&L.xtA[0][kp] = (unsigned)h0 | ((unsigned)h1 << 16);
        *(unsigned*)&L.xtA[0][kp + 2] = (unsigned)h2 | ((unsigned)h3 << 16);
        *(unsigned*)&L.xtA[1][kp] = (unsigned)u0 | ((unsigned)u1 << 16);
        *(unsigned*)&L.xtA[1][kp + 2] = (unsigned)u2 | ((unsigned)u3 << 16);
      }

      // ---- stage raw h to LDS, swizzled; row j, u64-pos tid: blk=tid>>1, half=tid&1 ----
      {
        const int blkk = tid >> 1;
        const int half = (tid & 1) << 2;
#pragma unroll
        for (int j = 0; j < 20; ++j) {
          *(u64_t*)&L.hnA[(j << 10) + ((blkk ^ (j & 15)) << 3) + half] = hv[j];
        }
      }
      __syncthreads();

      // ---- prefetch e/m for t+1, this batch (covered by MFMA + tail) ----
      if (t + 1 < S) {
        evv[ph] = ((const f4_t*)e)[(size_t)(b * S + t + 1) * 256 + tid];
        mvv[ph] = ((const f4_t*)m)[(size_t)(b * S + t + 1) * 256 + tid];
      }

      // ---- MFMA on RAW h: h@U^T (split U), Wx (xt hi/lo rows, split W), gate h.xt ----
      f4_t cU00 = {0, 0, 0, 0}, cU01 = {0, 0, 0, 0}, cU10 = {0, 0, 0, 0}, cU11 = {0, 0, 0, 0};
      f4_t cW0 = {0, 0, 0, 0}, cW1 = {0, 0, 0, 0}, cG0 = {0, 0, 0, 0}, cG1 = {0, 0, 0, 0};
      {
        const int r1 = 16 + (l15 < 4 ? l15 : 3);  // rows 20..31 duplicate row 19 (ignored)
#pragma unroll
        for (int kf = 0; kf < 8; ++kf) {
          const int blk = (wv << 5) + (kf << 2) + lo4;  // 8-elem k-block index, 0..127
          const s8_t a0 = *(const s8_t*)&L.hnA[(l15 << 10) + ((blk ^ l15) << 3)];
          const s8_t a1 = *(const s8_t*)&L.hnA[(r1 << 10) + ((blk ^ (r1 & 15)) << 3)];
          const s8_t ax = *(const s8_t*)&L.xtA[l15 & 1][blk << 3];
          cU00 = MFMA(a0, BUh[0][kf], cU00);
          cU00 = MFMA(a0, BUl[0][kf], cU00);
          cU01 = MFMA(a0, BUh[1][kf], cU01);
          cU01 = MFMA(a0, BUl[1][kf], cU01);
          cU10 = MFMA(a1, BUh[0][kf], cU10);
          cU10 = MFMA(a1, BUl[0][kf], cU10);
          cU11 = MFMA(a1, BUh[1][kf], cU11);
          cU11 = MFMA(a1, BUl[1][kf], cU11);
          cW0 = MFMA(ax, BWh[0][kf], cW0);
          cW0 = MFMA(ax, BWl[0][kf], cW0);
          cW1 = MFMA(ax, BWh[1][kf], cW1);
          cW1 = MFMA(ax, BWl[1][kf], cW1);
          cG0 = MFMA(ax, a0, cG0);  // gate: xt(hi,lo rows) @ h_raw^T
          cG1 = MFMA(ax, a1, cG1);
        }
      }

      // ---- single-pass reduction: each wave writes its own copy ----
#pragma unroll
      for (int q = 0; q < 4; ++q) {
        const int r = (lo4 << 2) + q;
        L.credU[wv][0][0][r][l15] = cU00[q];
        L.credU[wv][0][1][r][l15] = cU01[q];
        L.credU[wv][1][0][r][l15] = cU10[q];
        L.credU[wv][1][1][r][l15] = cU11[q];
      }
      if (lo4 == 0) {
        L.wxAcc[wv][0][l15] = cW0[0] + cW0[1];   // row0(hi)+row1(lo)
        L.wxAcc[wv][1][l15] = cW1[0] + cW1[1];
        L.gAcc[wv][0][l15] = cG0[0] + cG0[1];
        L.gAcc[wv][1][l15] = cG1[0] + cG1[1];
      }
      if (tid < 160) L.rowsq[tid >> 3][tid & 7] = np4;
      __syncthreads();

      // ---- sL + gate + Wx finalize (deferred norm: pre = s*(h_raw.xt) + kx) ----
      if (tid < NB) {
        float sq = 0.f;
#pragma unroll
        for (int q = 0; q < 8; ++q) sq += L.rowsq[tid][q];
        const float s = 1.0f / (sqrtf(sq) + EPS);
        L.sL[tid] = s;
        const int mt = tid >> 4, ccc = tid & 15;
        const float pre = s * (L.gAcc[0][mt][ccc] + L.gAcc[1][mt][ccc] +
                               L.gAcc[2][mt][ccc] + L.gAcc[3][mt][ccc]) + kx;
        L.gL[tid] = 1.0f / (1.0f + expf(-pre));
      } else if (tid >= 32 && tid < 64) {
        const int c = tid - 32;
        const int nt = c >> 4, ccc = c & 15;
        L.wxS[c] = L.wxAcc[0][nt][ccc] + L.wxAcc[1][nt][ccc] +
                   L.wxAcc[2][nt][ccc] + L.wxAcc[3][nt][ccc];
      }
      __syncthreads();

      // ---- update: cand=tanh(s*hU+KV+Wx); h'=s*h+g*cand; publish (coherent stores) ----
      if (tid < 160) {
        const int i = tid >> 3, c4 = (tid & 7) << 2;
        const int mt = i >> 4, r = i & 15, nt = c4 >> 4, ccc = c4 & 15;
        const f4_t sU = *(const f4_t*)&L.credU[0][mt][nt][r][ccc] +
                        *(const f4_t*)&L.credU[1][mt][nt][r][ccc] +
                        *(const f4_t*)&L.credU[2][mt][nt][r][ccc] +
                        *(const f4_t*)&L.credU[3][mt][nt][r][ccc];
        const f4_t kv = *(const f4_t*)&L.KVs[i][c4];
        const f4_t wx = *(const f4_t*)&L.wxS[c4];
        const f4_t oh = *(const f4_t*)&L.ownH[ph][i][c4];
        const float s = L.sL[i], g = L.gL[i];
        f4_t hn;
        float sq = 0.f;
#pragma unroll
        for (int u = 0; u < 4; ++u) {
          const float cand = tanhf(s * sU[u] + kv[u] + wx[u]);
          const float hv2 = s * oh[u] + g * cand;
          hn[u] = hv2;
          sq += hv2 * hv2;
        }
        *(f4_t*)&L.ownH[ph][i][c4] = hn;
        const unsigned d0 = (unsigned)f2bf(hn[0]) | ((unsigned)f2bf(hn[1]) << 16);
        const unsigned d1 = (unsigned)f2bf(hn[2]) | ((unsigned)f2bf(hn[3]) << 16);
        u64_t* hb8 = (u64_t*)Hbuf + (size_t)(nxt * B + b) * (NB * 256) +
                     (i << 8) + (wg << 3) + (c4 >> 2);
        ASTORE64(hb8, (u64_t)d0 | ((u64_t)d1 << 32));
        // fold sumsq over the 8 threads of row i (8-aligned lanes, same wave)
        sq += __shfl_xor(sq, 1);
        sq += __shfl_xor(sq, 2);
        sq += __shfl_xor(sq, 4);
        if ((tid & 7) == 0) {
          unsigned* np = (unsigned*)NormP + ((size_t)(nxt * B + b) * NB + i) * NWG + wg;
          __hip_atomic_store(np, __float_as_uint(sq), __ATOMIC_RELAXED,
                             __HIP_MEMORY_SCOPE_AGENT);
        }
      }
      __syncthreads();  // drains all threads' stores (vmcnt 0 before s_barrier)

      // ---- release: bump this batch's counter ----
      if (tid == 0) {
        __hip_atomic_fetch_add(myctr, 1, __ATOMIC_RELEASE, __HIP_MEMORY_SCOPE_AGENT);
      }
    }
  }

  // ---- final: per batch, poll last release, reduce NormP(parity 0), write out ----
#pragma unroll
  for (int ph = 0; ph < 2; ++ph) {
    const int b = bA + ph;
    int* const myctr = ctr + b * 16;
    if (tid == 0) {
      while (__hip_atomic_load(myctr, __ATOMIC_RELAXED, __HIP_MEMORY_SCOPE_AGENT) < NWG * S)
        __builtin_amdgcn_s_sleep(1);
    }
    __syncthreads();
    if (tid < 160) {
      const int i = tid >> 3;
      u64_t* np8 = (u64_t*)NormP + ((size_t)(0 * B + b) * NB + i) * 16 + ((tid & 7) << 1);
      const u64_t x0 = ALOAD64(np8);
      const u64_t x1 = ALOAD64(np8 + 1);
      L.rowsq[i][tid & 7] = u64lo(x0) + u64hi(x0) + u64lo(x1) + u64hi(x1);
    }
    __syncthreads();
    if (tid < NB) {
      float sq = 0.f;
#pragma unroll
      for (int q = 0; q < 8; ++q) sq += L.rowsq[tid][q];
      L.sL[tid] = 1.0f / (sqrtf(sq) + EPS);
    }
    __syncthreads();
    if (tid < 160) {
      const int i = tid >> 3, c4 = (tid & 7) << 2;
      const float s = L.sL[i];
      const f4_t oh = *(const f4_t*)&L.ownH[ph][i][c4];
      f4_t o;
#pragma unroll
      for (int u = 0; u < 4; ++u) o[u] = s * oh[u];
      *(f4_t*)(out + (size_t)b * NB * D + (size_t)i * D + (wg << 5) + c4) = o;
    }
    __syncthreads();  // rowsq/sL reused by next ph
  }
}

}  // namespace

extern "C" void kernel_launch(void* const* d_in, const int* in_sizes, int n_in,
                              void* d_out, int out_size, void* d_ws, size_t ws_size,
                              hipStream_t stream) {
  const float* e = (const float*)d_in[0];
  const float* m = (const float*)d_in[1];
  const float* state = (const float*)d_in[2];
  const float* U = (const float*)d_in[3];
  const float* V = (const float*)d_in[4];
  const float* W = (const float*)d_in[5];
  const float* keys = (const float*)d_in[6];
  float* out = (float*)d_out;
  char* ws = (char*)d_ws;

  unsigned* Hbuf = (unsigned*)(ws + OFF_HBUF);
  float* NormP = (float*)(ws + OFF_NORM);
  int* ctr = (int*)(ws + OFF_CTR);
  float* KV = (float*)(ws + OFF_KV);
  float* KX = (float*)(ws + OFF_KX);
  unsigned short* Uhi = (unsigned short*)(ws + OFF_UHI);
  unsigned short* Ulo = (unsigned short*)(ws + OFF_ULO);
  unsigned short* Whi = (unsigned short*)(ws + OFF_WHI);
  unsigned short* Wlo = (unsigned short*)(ws + OFF_WLO);

  k_convert<<<512, 256, 0, stream>>>(U, W, Uhi, Ulo, Whi, Wlo);
  k_kv<<<16, 256, 0, stream>>>(keys, V, KV);
  k_kx<<<B * S, 256, 0, stream>>>(e, m, keys, KX);
  k_state<<<341, 256, 0, stream>>>(state, Hbuf, NormP, ctr);
  k_rnn<<<128, 256, 0, stream>>>(e, m, state, KX, KV, Uhi, Ulo, Whi, Wlo,
                                 Hbuf, NormP, ctr, out);
}

// Round 5
// 16997.371 us; speedup vs baseline: 2.2254x; 1.3133x over previous
//
#include <hip/hip_runtime.h>
#include <cstdint>
#include <cstddef>

namespace {

constexpr int D   = 1024;
constexpr int NB  = 20;
constexpr int B   = 8;
constexpr int S   = 2048;
constexpr int NWG = 32;      // workgroups cooperating per batch
constexpr float EPS = 1e-8f;

typedef __attribute__((ext_vector_type(4))) float f4_t;
typedef __attribute__((ext_vector_type(8))) short s8_t;
typedef unsigned long long u64_t;

__device__ __forceinline__ unsigned short f2bf(float f) {
  unsigned u = __float_as_uint(f);
  u += 0x7fffu + ((u >> 16) & 1u);     // RNE
  return (unsigned short)(u >> 16);
}
__device__ __forceinline__ float bf2f(unsigned short h) {
  return __uint_as_float(((unsigned)h) << 16);
}
__device__ __forceinline__ float u64lo(u64_t x) { return __uint_as_float((unsigned)x); }
__device__ __forceinline__ float u64hi(u64_t x) { return __uint_as_float((unsigned)(x >> 32)); }
__device__ __forceinline__ float sigm_fast(float x) { return 1.0f / (1.0f + __expf(-x)); }
__device__ __forceinline__ float tanh_fast(float x) {
  const float e = __expf(2.0f * x);
  return 1.0f - 2.0f / (e + 1.0f);
}

#define MFMA(a, b, c) __builtin_amdgcn_mfma_f32_16x16x32_bf16((a), (b), (c), 0, 0, 0)
#define ALOAD64(p) __hip_atomic_load((p), __ATOMIC_RELAXED, __HIP_MEMORY_SCOPE_AGENT)
#define ASTORE64(p, v) __hip_atomic_store((p), (v), __ATOMIC_RELAXED, __HIP_MEMORY_SCOPE_AGENT)

// ---- workspace layout (bytes) ----
constexpr size_t OFF_HBUF = 0;                                   // u32 [2][B][NB][512]  (bf16 pairs)
constexpr size_t OFF_NORM = OFF_HBUF + 2ull * B * NB * 512 * 4;  // f32 [2][B][NB][NWG]
constexpr size_t OFF_CTR  = OFF_NORM + 2ull * B * NB * NWG * 4;  // i32 [B][32] (128B apart)
constexpr size_t OFF_KV   = OFF_CTR + (size_t)B * 32 * 4;        // f32 [NB][D]
constexpr size_t OFF_KX   = OFF_KV + (size_t)NB * D * 4;         // f32 [B*S][NB]
constexpr size_t OFF_UHI  = OFF_KX + (size_t)B * S * NB * 4;     // u16 [D][D]
constexpr size_t OFF_ULO  = OFF_UHI + (size_t)D * D * 2;
constexpr size_t OFF_WHI  = OFF_ULO + (size_t)D * D * 2;
constexpr size_t OFF_WLO  = OFF_WHI + (size_t)D * D * 2;

// ---------------- init kernels ----------------

__global__ void k_convert(const float* __restrict__ U, const float* __restrict__ W,
                          unsigned short* __restrict__ Uhi, unsigned short* __restrict__ Ulo,
                          unsigned short* __restrict__ Whi, unsigned short* __restrict__ Wlo) {
  const int n = D * D;
  for (int i = blockIdx.x * blockDim.x + threadIdx.x; i < n; i += gridDim.x * blockDim.x) {
    float u = U[i];
    unsigned short h = f2bf(u);
    Uhi[i] = h;
    Ulo[i] = f2bf(u - bf2f(h));
    float w = W[i];
    h = f2bf(w);
    Whi[i] = h;
    Wlo[i] = f2bf(w - bf2f(h));
  }
}

// KV[i][j] = keys[i] . V[j]
__global__ void k_kv(const float* __restrict__ keys, const float* __restrict__ V,
                     float* __restrict__ KV) {
  const int tid = threadIdx.x;
  const int j = blockIdx.x * 64 + (tid >> 2);
  const int kq = tid & 3;
  const f4_t* v4 = (const f4_t*)(V + (size_t)j * D + kq * 256);
  const f4_t* k4base = (const f4_t*)keys;
  float acc[NB];
#pragma unroll
  for (int i = 0; i < NB; ++i) acc[i] = 0.f;
  for (int q = 0; q < 64; ++q) {
    const f4_t v = v4[q];
#pragma unroll
    for (int i = 0; i < NB; ++i) {
      const f4_t kk = k4base[i * 256 + kq * 64 + q];
      acc[i] += kk[0] * v[0] + kk[1] * v[1] + kk[2] * v[2] + kk[3] * v[3];
    }
  }
#pragma unroll
  for (int i = 0; i < NB; ++i) {
    float s = acc[i];
    s += __shfl_xor(s, 1);
    s += __shfl_xor(s, 2);
    if (kq == 0) KV[(size_t)i * D + j] = s;
  }
}

// KX[bt][i] = keys[i] . (e[bt]+m[bt])
__global__ void k_kx(const float* __restrict__ e, const float* __restrict__ m,
                     const float* __restrict__ keys, float* __restrict__ KX) {
  __shared__ f4_t xs[256];
  __shared__ float part[NB][8];
  const int bt = blockIdx.x, tid = threadIdx.x;
  xs[tid] = ((const f4_t*)e)[(size_t)bt * 256 + tid] + ((const f4_t*)m)[(size_t)bt * 256 + tid];
  __syncthreads();
  if (tid < 160) {
    const int i = tid >> 3, s8 = tid & 7;
    float acc = 0.f;
    const f4_t* k4 = (const f4_t*)keys + i * 256 + s8 * 32;
    for (int q = 0; q < 32; ++q) {
      const f4_t kk = k4[q];
      const f4_t xx = xs[s8 * 32 + q];
      acc += kk[0] * xx[0] + kk[1] * xx[1] + kk[2] * xx[2] + kk[3] * xx[3];
    }
    part[i][s8] = acc;
  }
  __syncthreads();
  if (tid < NB) {
    float s = 0.f;
#pragma unroll
    for (int q = 0; q < 8; ++q) s += part[tid][q];
    KX[(size_t)bt * NB + tid] = s;
  }
}

__global__ void k_state(const float* __restrict__ state, unsigned* __restrict__ Hbuf,
                        float* __restrict__ NormP, int* __restrict__ ctr) {
  const int idx = blockIdx.x * 256 + threadIdx.x;
  if (idx < B * NB * 512) {
    const int r = idx % (NB * 512);
    const int i = r >> 9, d2 = (r & 511) << 1;
    const unsigned short a = f2bf(state[i * D + d2]);
    const unsigned short c = f2bf(state[i * D + d2 + 1]);
    Hbuf[idx] = (unsigned)a | ((unsigned)c << 16);
  }
  const int j = idx - B * NB * 512;
  if (j >= 0 && j < B * NB * NWG) NormP[j] = 1.0f / 32.0f;  // sumsq=1 -> s=1 exactly
  const int q = idx - B * NB * 512 - B * NB * NWG;
  if (q >= 0 && q < B * 32) ctr[q] = 0;
}

// ---------------- persistent recurrence kernel ----------------
// 128 blocks; block = (pair of batches {2p,2p+1}) x (column slice wg of 32).
// Software-pipelined: while computing batch b's step, the block polls+gathers
// the OTHER batch's state, hiding exchange RTTs under compute.

struct __align__(16) LdsT {
  unsigned short hnA[2][NB * 1024]; // per-batch raw bf16 h, swizzled   (80 KB)
  unsigned short xtA[2][2][1024];   // per-batch xt hi/lo rows           (8 KB)
  float credU[4][2][2][16][20];     // per-wave copies [wv][mt][nt][row][col pad20] (20 KB)
  float wxAcc[4][2][16];            // [wv][nt][col]
  float gAcc[4][2][16];             // [wv][mt][col]
  float KVs[NB][32];                // batch-independent
  float ownH[2][NB][32];            // per-batch fp32 unnormalized h slice
};

__device__ __forceinline__ void build_xt(unsigned short* xt /* [2][1024] */, int tid, f4_t x) {
  const unsigned short h0 = f2bf(x[0]), h1 = f2bf(x[1]), h2 = f2bf(x[2]), h3 = f2bf(x[3]);
  const unsigned short u0 = f2bf(x[0] - bf2f(h0)), u1 = f2bf(x[1] - bf2f(h1));
  const unsigned short u2 = f2bf(x[2] - bf2f(h2)), u3 = f2bf(x[3] - bf2f(h3));
  const int kp = tid << 2;
  *(unsigned*)&xt[kp] = (unsigned)h0 | ((unsigned)h1 << 16);
  *(unsigned*)&xt[kp + 2] = (unsigned)h2 | ((unsigned)h3 << 16);
  *(unsigned*)&xt[1024 + kp] = (unsigned)u0 | ((unsigned)u1 << 16);
  *(unsigned*)&xt[1024 + kp + 2] = (unsigned)u2 | ((unsigned)u3 << 16);
}

__device__ __forceinline__ void stage_h(unsigned short* hn, int tid, const u64_t* hv) {
  const int blkk = tid >> 1;
  const int half = (tid & 1) << 2;
#pragma unroll
  for (int j = 0; j < 20; ++j)
    *(u64_t*)&hn[(j << 10) + ((blkk ^ (j & 15)) << 3) + half] = hv[j];
}

__launch_bounds__(256, 1)
__global__ void k_rnn(const float* __restrict__ e, const float* __restrict__ m,
                      const float* __restrict__ state,
                      const float* __restrict__ KX, const float* __restrict__ KV,
                      const unsigned short* __restrict__ Uhi, const unsigned short* __restrict__ Ulo,
                      const unsigned short* __restrict__ Whi, const unsigned short* __restrict__ Wlo,
                      unsigned* __restrict__ Hbuf, float* __restrict__ NormP,
                      int* __restrict__ ctr, float* __restrict__ out) {
  __shared__ LdsT L;
  const int tid = threadIdx.x;
  const int pair = (blockIdx.x >> 1) & 3;
  const int bA = pair << 1;
  const int wg = ((blockIdx.x & 1) << 4) | (blockIdx.x >> 3);  // 0..31 column slice
  const int wv = tid >> 6;
  const int ln = tid & 63;
  const int l15 = ln & 15;
  const int lo4 = ln >> 4;

  // resident B-fragments: U and W column slices, bf16 hi/lo, this wave's k-chunk.
  s8_t BUh[2][8], BUl[2][8], BWh[2][8], BWl[2][8];
  {
    const int rowb = (wg << 5) + l15;
#pragma unroll
    for (int nt = 0; nt < 2; ++nt)
#pragma unroll
      for (int kf = 0; kf < 8; ++kf) {
        const size_t off = (size_t)(rowb + nt * 16) * D + (wv << 8) + (kf << 5) + (lo4 << 3);
        BUh[nt][kf] = *(const s8_t*)(Uhi + off);
        BUl[nt][kf] = *(const s8_t*)(Ulo + off);
        BWh[nt][kf] = *(const s8_t*)(Whi + off);
        BWl[nt][kf] = *(const s8_t*)(Wlo + off);
      }
  }
  if (tid < 160) {
    const int i = tid >> 3, c4 = (tid & 7) << 2;
    const f4_t h0 = *(const f4_t*)(state + (size_t)i * D + (wg << 5) + c4);
    *(f4_t*)&L.ownH[0][i][c4] = h0;
    *(f4_t*)&L.ownH[1][i][c4] = h0;
    *(f4_t*)&L.KVs[i][c4] = *(const f4_t*)(KV + (size_t)i * D + (wg << 5) + c4);
  }

  f4_t evv[2], mvv[2];
  float sreg[2] = {1.f, 1.f}, kxreg[2] = {0.f, 0.f};

  // ---- bootstrap: stage batch A step 0 ----
  {
    u64_t hv[20];
    const u64_t* hb8 = (const u64_t*)Hbuf + (size_t)(0 * B + bA) * (NB * 256);
#pragma unroll
    for (int j = 0; j < 20; ++j) hv[j] = ALOAD64(hb8 + j * 256 + tid);
    float np4 = 0.f;
    if (tid < 160) {
      const int i = tid >> 3;
      const u64_t* np8 = (const u64_t*)NormP + ((size_t)(0 * B + bA) * NB + i) * 16 + ((tid & 7) << 1);
      const u64_t x0 = ALOAD64(np8);
      const u64_t x1 = ALOAD64(np8 + 1);
      np4 = u64lo(x0) + u64hi(x0) + u64lo(x1) + u64hi(x1);
    }
    const f4_t ev0 = ((const f4_t*)e)[(size_t)(bA * S) * 256 + tid];
    const f4_t mv0 = ((const f4_t*)m)[(size_t)(bA * S) * 256 + tid];
    build_xt(&L.xtA[0][0][0], tid, ev0 + mv0);
    stage_h(L.hnA[0], tid, hv);
    if (tid < 160) {
      float sq = np4;
      sq += __shfl_xor(sq, 1);
      sq += __shfl_xor(sq, 2);
      sq += __shfl_xor(sq, 4);
      sreg[0] = 1.0f / (sqrtf(sq) + EPS);
      kxreg[0] = KX[(size_t)(bA * S) * NB + (tid >> 3)];
    }
    evv[0] = ((const f4_t*)e)[(size_t)(bA * S + 1) * 256 + tid];
    mvv[0] = ((const f4_t*)m)[(size_t)(bA * S + 1) * 256 + tid];
    evv[1] = ((const f4_t*)e)[(size_t)((bA + 1) * S) * 256 + tid];
    mvv[1] = ((const f4_t*)m)[(size_t)((bA + 1) * S) * 256 + tid];
  }
  __syncthreads();

  for (int t = 0; t < S; ++t) {
    const int nxt = (t + 1) & 1;
#pragma unroll
    for (int ph = 0; ph < 2; ++ph) {
      const int b = bA + ph;
      const int o = ph ^ 1;
      const int ob = bA + o;
      const int to = t + ph;  // step being prepped for batch ob

      // ---- compute batch b step t from staged hnA[ph]/xtA[ph] ----
      f4_t cU00 = {0, 0, 0, 0}, cU01 = {0, 0, 0, 0}, cU10 = {0, 0, 0, 0}, cU11 = {0, 0, 0, 0};
      f4_t cW0 = {0, 0, 0, 0}, cW1 = {0, 0, 0, 0}, cG0 = {0, 0, 0, 0}, cG1 = {0, 0, 0, 0};
      {
        const unsigned short* hb = L.hnA[ph];
        const unsigned short* xb = &L.xtA[ph][0][0];
        const int r1 = 16 + (l15 < 4 ? l15 : 3);  // rows 20..31 duplicate row 19 (ignored)
#pragma unroll
        for (int kf = 0; kf < 8; ++kf) {
          const int blk = (wv << 5) + (kf << 2) + lo4;  // 8-elem k-block index, 0..127
          const s8_t a0 = *(const s8_t*)&hb[(l15 << 10) + ((blk ^ l15) << 3)];
          const s8_t a1 = *(const s8_t*)&hb[(r1 << 10) + ((blk ^ (r1 & 15)) << 3)];
          const s8_t ax = *(const s8_t*)&xb[(l15 & 1) * 1024 + (blk << 3)];
          cU00 = MFMA(a0, BUh[0][kf], cU00);
          cU00 = MFMA(a0, BUl[0][kf], cU00);
          cU01 = MFMA(a0, BUh[1][kf], cU01);
          cU01 = MFMA(a0, BUl[1][kf], cU01);
          cU10 = MFMA(a1, BUh[0][kf], cU10);
          cU10 = MFMA(a1, BUl[0][kf], cU10);
          cU11 = MFMA(a1, BUh[1][kf], cU11);
          cU11 = MFMA(a1, BUl[1][kf], cU11);
          cW0 = MFMA(ax, BWh[0][kf], cW0);
          cW0 = MFMA(ax, BWl[0][kf], cW0);
          cW1 = MFMA(ax, BWh[1][kf], cW1);
          cW1 = MFMA(ax, BWl[1][kf], cW1);
          cG0 = MFMA(ax, a0, cG0);
          cG1 = MFMA(ax, a1, cG1);
        }
      }
#pragma unroll
      for (int q = 0; q < 4; ++q) {
        const int r = (lo4 << 2) + q;
        L.credU[wv][0][0][r][l15] = cU00[q];
        L.credU[wv][0][1][r][l15] = cU01[q];
        L.credU[wv][1][0][r][l15] = cU10[q];
        L.credU[wv][1][1][r][l15] = cU11[q];
      }
      if (lo4 == 0) {
        L.wxAcc[wv][0][l15] = cW0[0] + cW0[1];
        L.wxAcc[wv][1][l15] = cW1[0] + cW1[1];
        L.gAcc[wv][0][l15] = cG0[0] + cG0[1];
        L.gAcc[wv][1][l15] = cG1[0] + cG1[1];
      }
      __syncthreads();  // S1: cred/wx/g visible

      // ---- update + publish ----
      if (tid < 160) {
        const int i = tid >> 3, c4 = (tid & 7) << 2;
        const int mt = i >> 4, r = i & 15, nt = c4 >> 4, ccc = c4 & 15;
        const f4_t sU = *(const f4_t*)&L.credU[0][mt][nt][r][ccc] +
                        *(const f4_t*)&L.credU[1][mt][nt][r][ccc] +
                        *(const f4_t*)&L.credU[2][mt][nt][r][ccc] +
                        *(const f4_t*)&L.credU[3][mt][nt][r][ccc];
        const f4_t wx = *(const f4_t*)&L.wxAcc[0][nt][ccc] +
                        *(const f4_t*)&L.wxAcc[1][nt][ccc] +
                        *(const f4_t*)&L.wxAcc[2][nt][ccc] +
                        *(const f4_t*)&L.wxAcc[3][nt][ccc];
        const f4_t kv = *(const f4_t*)&L.KVs[i][c4];
        const f4_t oh = *(const f4_t*)&L.ownH[ph][i][c4];
        const float s = sreg[ph];
        const float gpre = s * (L.gAcc[0][mt][i & 15] + L.gAcc[1][mt][i & 15] +
                                L.gAcc[2][mt][i & 15] + L.gAcc[3][mt][i & 15]) + kxreg[ph];
        const float g = sigm_fast(gpre);
        f4_t hn;
        float sq = 0.f;
#pragma unroll
        for (int u = 0; u < 4; ++u) {
          const float cand = tanh_fast(s * sU[u] + kv[u] + wx[u]);
          const float hv2 = s * oh[u] + g * cand;
          hn[u] = hv2;
          sq += hv2 * hv2;
        }
        *(f4_t*)&L.ownH[ph][i][c4] = hn;
        const unsigned d0 = (unsigned)f2bf(hn[0]) | ((unsigned)f2bf(hn[1]) << 16);
        const unsigned d1 = (unsigned)f2bf(hn[2]) | ((unsigned)f2bf(hn[3]) << 16);
        u64_t* hb8 = (u64_t*)Hbuf + (size_t)(nxt * B + b) * (NB * 256) +
                     (i << 8) + (wg << 3) + (c4 >> 2);
        ASTORE64(hb8, (u64_t)d0 | ((u64_t)d1 << 32));
        sq += __shfl_xor(sq, 1);
        sq += __shfl_xor(sq, 2);
        sq += __shfl_xor(sq, 4);
        if ((tid & 7) == 0) {
          unsigned* np = (unsigned*)NormP + ((size_t)(nxt * B + b) * NB + i) * NWG + wg;
          __hip_atomic_store(np, __float_as_uint(sq), __ATOMIC_RELAXED,
                             __HIP_MEMORY_SCOPE_AGENT);
        }
      }
      __syncthreads();  // S3: drains publish stores (vmcnt 0 before s_barrier)

      // ---- release this batch (relaxed: payload already at LLC) ----
      if (tid == 0)
        __hip_atomic_fetch_add(ctr + b * 32, 1, __ATOMIC_RELAXED, __HIP_MEMORY_SCOPE_AGENT);

      // ---- prep other batch's step `to` (spin + gather + stage) ----
      if (to < S) {
        const int top = to & 1;
        const int tgt = NWG * to;
        while (__hip_atomic_load(ctr + ob * 32, __ATOMIC_RELAXED, __HIP_MEMORY_SCOPE_AGENT) < tgt)
          __builtin_amdgcn_s_sleep(2);
        u64_t hv[20];
        const u64_t* hb8 = (const u64_t*)Hbuf + (size_t)(top * B + ob) * (NB * 256);
#pragma unroll
        for (int j = 0; j < 20; ++j) hv[j] = ALOAD64(hb8 + j * 256 + tid);
        float np4 = 0.f;
        if (tid < 160) {
          const int i = tid >> 3;
          const u64_t* np8 = (const u64_t*)NormP + ((size_t)(top * B + ob) * NB + i) * 16 + ((tid & 7) << 1);
          const u64_t x0 = ALOAD64(np8);
          const u64_t x1 = ALOAD64(np8 + 1);
          np4 = u64lo(x0) + u64hi(x0) + u64lo(x1) + u64hi(x1);
        }
        // xt for (ob, to) from prefetched regs; overlaps gather flight
        build_xt(&L.xtA[o][0][0], tid, evv[o] + mvv[o]);
        if (to + 1 < S) {
          evv[o] = ((const f4_t*)e)[(size_t)(ob * S + to + 1) * 256 + tid];
          mvv[o] = ((const f4_t*)m)[(size_t)(ob * S + to + 1) * 256 + tid];
        }
        stage_h(L.hnA[o], tid, hv);
        if (tid < 160) {
          float sq = np4;
          sq += __shfl_xor(sq, 1);
          sq += __shfl_xor(sq, 2);
          sq += __shfl_xor(sq, 4);
          sreg[o] = 1.0f / (sqrtf(sq) + EPS);
          kxreg[o] = KX[(size_t)(ob * S + to) * NB + (tid >> 3)];
        }
      }
      __syncthreads();  // S2: staged data visible for next half-phase
    }
  }

  // ---- final: per batch, wait last release, reduce NormP(parity 0), write out ----
#pragma unroll
  for (int ph = 0; ph < 2; ++ph) {
    const int b = bA + ph;
    while (__hip_atomic_load(ctr + b * 32, __ATOMIC_RELAXED, __HIP_MEMORY_SCOPE_AGENT) < NWG * S)
      __builtin_amdgcn_s_sleep(2);
    if (tid < 160) {
      const int i = tid >> 3, c4 = (tid & 7) << 2;
      const u64_t* np8 = (const u64_t*)NormP + ((size_t)(0 * B + b) * NB + i) * 16 + ((tid & 7) << 1);
      const u64_t x0 = ALOAD64(np8);
      const u64_t x1 = ALOAD64(np8 + 1);
      float sq = u64lo(x0) + u64hi(x0) + u64lo(x1) + u64hi(x1);
      sq += __shfl_xor(sq, 1);
      sq += __shfl_xor(sq, 2);
      sq += __shfl_xor(sq, 4);
      const float s = 1.0f / (sqrtf(sq) + EPS);
      const f4_t oh = *(const f4_t*)&L.ownH[ph][i][c4];
      f4_t ov;
#pragma unroll
      for (int u = 0; u < 4; ++u) ov[u] = s * oh[u];
      *(f4_t*)(out + (size_t)b * NB * D + (size_t)i * D + (wg << 5) + c4) = ov;
    }
  }
}

}  // namespace

extern "C" void kernel_launch(void* const* d_in, const int* in_sizes, int n_in,
                              void* d_out, int out_size, void* d_ws, size_t ws_size,
                              hipStream_t stream) {
  const float* e = (const float*)d_in[0];
  const float* m = (const float*)d_in[1];
  const float* state = (const float*)d_in[2];
  const float* U = (const float*)d_in[3];
  const float* V = (const float*)d_in[4];
  const float* W = (const float*)d_in[5];
  const float* keys = (const float*)d_in[6];
  float* out = (float*)d_out;
  char* ws = (char*)d_ws;

  unsigned* Hbuf = (unsigned*)(ws + OFF_HBUF);
  float* NormP = (float*)(ws + OFF_NORM);
  int* ctr = (int*)(ws + OFF_CTR);
  float* KV = (float*)(ws + OFF_KV);
  float* KX = (float*)(ws + OFF_KX);
  unsigned short* Uhi = (unsigned short*)(ws + OFF_UHI);
  unsigned short* Ulo = (unsigned short*)(ws + OFF_ULO);
  unsigned short* Whi = (unsigned short*)(ws + OFF_WHI);
  unsigned short* Wlo = (unsigned short*)(ws + OFF_WLO);

  k_convert<<<512, 256, 0, stream>>>(U, W, Uhi, Ulo, Whi, Wlo);
  k_kv<<<16, 256, 0, stream>>>(keys, V, KV);
  k_kx<<<B * S, 256, 0, stream>>>(e, m, keys, KX);
  k_state<<<342, 256, 0, stream>>>(state, Hbuf, NormP, ctr);
  k_rnn<<<128, 256, 0, stream>>>(e, m, state, KX, KV, Uhi, Ulo, Whi, Wlo,
                                 Hbuf, NormP, ctr, out);
}